// Round 7
// baseline (459.467 us; speedup 1.0000x reference)
//
#include <hip/hip_runtime.h>
#include <hip/hip_bf16.h>
#include <math.h>

#define N_NODES 50000
#define N_EDGES 800000
#define DIM 256
#define HEADS 8
#define LAMBDA_INIT 0.63212055882855767f

using bf16x8 = __attribute__((ext_vector_type(8))) short;
using bf16x4 = __attribute__((ext_vector_type(4))) short;
using f32x4  = __attribute__((ext_vector_type(4))) float;
using f32x2  = __attribute__((ext_vector_type(2))) float;
#define MFMA16(a, b, c) __builtin_amdgcn_mfma_f32_16x16x32_bf16(a, b, c, 0, 0, 0)

__device__ __forceinline__ short f2b(float f) {
    __hip_bfloat16 h = __float2bfloat16(f);
    return *reinterpret_cast<short*>(&h);
}
__device__ __forceinline__ float b2f(short s) {
    unsigned u = ((unsigned)(unsigned short)s) << 16;
    return __uint_as_float(u);
}
// pack 2 f32 -> 2 bf16 (RNE), single instruction
__device__ __forceinline__ unsigned cvt_pk_bf16(float a, float b) {
    unsigned r;
    asm("v_cvt_pk_bf16_f32 %0, %1, %2" : "=v"(r) : "v"(a), "v"(b));
    return r;
}

// GELU, relu-form: gelu(x) = max(x,0) - |x| * q'(t) * exp(-x^2/2),
// q' = 0.5*(a1 t + a2 t^2 + a3 t^3), t = 1/(1+0.47047*|x|/sqrt2)
// (A&S 7.1.25, |erf err| <= 2.5e-5 -- far below bf16 quantization)
__device__ __forceinline__ float gelu_f(float x) {
    float az = 0.70710678118654752f * fabsf(x);
    float t  = __builtin_amdgcn_rcpf(fmaf(0.47047f, az, 1.f));
    float q  = fmaf(fmaf(0.3739278f, t, -0.0479399f), t, 0.1740121f) * t;
    float E  = __expf(-az * az);
    return fmaf(-q * E, fabsf(x), fmaxf(x, 0.f));
}

// ---------- counting sort of edges by tgt (hist fused into edge_mlp) ----------
__global__ __launch_bounds__(256) void scan1(const int* __restrict__ cnt,
                                             int* __restrict__ offs,
                                             int* __restrict__ partials, int n) {
    __shared__ int sh[256];
    int i = blockIdx.x * 256 + threadIdx.x;
    int v = (i < n) ? cnt[i] : 0;
    sh[threadIdx.x] = v;
    __syncthreads();
    for (int s = 1; s < 256; s <<= 1) {
        int add = (threadIdx.x >= s) ? sh[threadIdx.x - s] : 0;
        __syncthreads();
        sh[threadIdx.x] += add;
        __syncthreads();
    }
    if (i < n) offs[i] = sh[threadIdx.x] - v;
    if (threadIdx.x == 255) partials[blockIdx.x] = sh[255];
}

// scan of block partials + beta computation (fused; both tiny, single block)
__global__ __launch_bounds__(256) void scan2(int* __restrict__ partials, int nb,
                                             const float* __restrict__ lq,
                                             const float* __restrict__ lk,
                                             float* __restrict__ beta_ws,
                                             float* __restrict__ beta_out) {
    __shared__ int sh[256];
    __shared__ float redb[128];
    int tid = threadIdx.x;
    int v = (tid < nb) ? partials[tid] : 0;
    sh[tid] = v;
    __syncthreads();
    for (int s = 1; s < 256; s <<= 1) {
        int add = (tid >= s) ? sh[tid - s] : 0;
        __syncthreads();
        sh[tid] += add;
        __syncthreads();
    }
    if (tid < nb) partials[tid] = sh[tid] - v;

    // ---- beta ----
    if (tid < 128) {
        float b = 0.f;
        for (int i = tid; i < 100; i += 128) b += lq[i] * lk[i];
        redb[tid] = b;
    }
    __syncthreads();
    for (int s = 64; s > 0; s >>= 1) {
        if (tid < s) redb[tid] += redb[tid + s];
        __syncthreads();
    }
    if (tid == 0) {
        float l1 = expf(redb[0]);
        float b = 1.f / (1.f + expf(-l1 * LAMBDA_INIT));
        *beta_ws = b;
        *beta_out = b;
    }
}

__global__ __launch_bounds__(256) void scan3(int* __restrict__ offs,
                                             const int* __restrict__ partials,
                                             int* __restrict__ cursor, int n) {
    int i = blockIdx.x * 256 + threadIdx.x;
    if (i < n) {
        int o = offs[i] + partials[blockIdx.x];
        offs[i] = o;
        cursor[i] = o;
    }
    if (i == 0) offs[n] = N_EDGES;
}

__global__ __launch_bounds__(256) void scatter_eid(const int* __restrict__ tgt,
                                                   int* __restrict__ cursor,
                                                   int* __restrict__ sorted_eid) {
    int e = blockIdx.x * 256 + threadIdx.x;
    if (e < N_EDGES) {
        int p = atomicAdd(&cursor[tgt[e]], 1);
        sorted_eid[p] = e;
    }
}

// ---------- bf16-MFMA GEMM: C[m,n] = sum_k A[m,k] * W[n,k] ----------
template <bool ABF, bool CBF>
__global__ __launch_bounds__(256) void gemm_mfma_t(const void* __restrict__ Av,
                                                   const float* __restrict__ W,
                                                   void* __restrict__ Cv, int M) {
    __shared__ __align__(16) short As[128 * 40];
    __shared__ __align__(16) short Ws[64 * 40];
    int tid = threadIdx.x;
    int lane = tid & 63, wv = tid >> 6;
    int l16 = lane & 15, quad = lane >> 4;
    int bm = blockIdx.x * 128, bn = blockIdx.y * 64;

    f32x4 acc[2][4];
#pragma unroll
    for (int mt = 0; mt < 2; ++mt)
#pragma unroll
        for (int nt = 0; nt < 4; ++nt) acc[mt][nt] = (f32x4){0.f, 0.f, 0.f, 0.f};

    int r = tid >> 1, hf = tid & 1;
    int rw = (tid & 127) >> 1, hw = tid & 1;

    for (int k0 = 0; k0 < 256; k0 += 32) {
        {
            int m = bm + r;
            bf16x8 p0, p1;
            if (ABF) {
                if (m < M) {
                    const bf16x8* ap =
                        (const bf16x8*)&((const short*)Av)[(size_t)m * 256 + k0 + hf * 16];
                    p0 = ap[0]; p1 = ap[1];
                } else {
                    p0 = (bf16x8){0,0,0,0,0,0,0,0}; p1 = p0;
                }
            } else {
                float4 f0, f1, f2, f3;
                if (m < M) {
                    const float4* ap =
                        (const float4*)&((const float*)Av)[(size_t)m * 256 + k0 + hf * 16];
                    f0 = ap[0]; f1 = ap[1]; f2 = ap[2]; f3 = ap[3];
                } else {
                    f0 = f1 = f2 = f3 = make_float4(0.f, 0.f, 0.f, 0.f);
                }
                p0[0]=f2b(f0.x); p0[1]=f2b(f0.y); p0[2]=f2b(f0.z); p0[3]=f2b(f0.w);
                p0[4]=f2b(f1.x); p0[5]=f2b(f1.y); p0[6]=f2b(f1.z); p0[7]=f2b(f1.w);
                p1[0]=f2b(f2.x); p1[1]=f2b(f2.y); p1[2]=f2b(f2.z); p1[3]=f2b(f2.w);
                p1[4]=f2b(f3.x); p1[5]=f2b(f3.y); p1[6]=f2b(f3.z); p1[7]=f2b(f3.w);
            }
            *(bf16x8*)&As[r * 40 + hf * 16]     = p0;
            *(bf16x8*)&As[r * 40 + hf * 16 + 8] = p1;
        }
        if (tid < 128) {
            const float4* wp = (const float4*)&W[(size_t)(bn + rw) * 256 + k0 + hw * 16];
            float4 f0 = wp[0], f1 = wp[1], f2 = wp[2], f3 = wp[3];
            bf16x8 p0, p1;
            p0[0]=f2b(f0.x); p0[1]=f2b(f0.y); p0[2]=f2b(f0.z); p0[3]=f2b(f0.w);
            p0[4]=f2b(f1.x); p0[5]=f2b(f1.y); p0[6]=f2b(f1.z); p0[7]=f2b(f1.w);
            p1[0]=f2b(f2.x); p1[1]=f2b(f2.y); p1[2]=f2b(f2.z); p1[3]=f2b(f2.w);
            p1[4]=f2b(f3.x); p1[5]=f2b(f3.y); p1[6]=f2b(f3.z); p1[7]=f2b(f3.w);
            *(bf16x8*)&Ws[rw * 40 + hw * 16]     = p0;
            *(bf16x8*)&Ws[rw * 40 + hw * 16 + 8] = p1;
        }
        __syncthreads();
#pragma unroll
        for (int mt = 0; mt < 2; ++mt) {
            bf16x8 afr = *(bf16x8*)&As[(wv * 32 + mt * 16 + l16) * 40 + quad * 8];
#pragma unroll
            for (int nt = 0; nt < 4; ++nt) {
                bf16x8 bfr = *(bf16x8*)&Ws[(nt * 16 + l16) * 40 + quad * 8];
                acc[mt][nt] = MFMA16(afr, bfr, acc[mt][nt]);
            }
        }
        __syncthreads();
    }
#pragma unroll
    for (int mt = 0; mt < 2; ++mt) {
#pragma unroll
        for (int rr = 0; rr < 4; ++rr) {
            int m = bm + wv * 32 + mt * 16 + quad * 4 + rr;
            if (m < M) {
#pragma unroll
                for (int nt = 0; nt < 4; ++nt) {
                    if (CBF)
                        ((short*)Cv)[(size_t)m * 256 + bn + nt * 16 + l16] =
                            f2b(acc[mt][nt][rr]);
                    else
                        ((float*)Cv)[(size_t)m * 256 + bn + nt * 16 + l16] =
                            acc[mt][nt][rr];
                }
            }
        }
    }
}

// ---------- edge MLP v6: v4 MFMA structure + poly GELU (round-5, verified
// fast) + v_cvt_pk_bf16_f32 packing + fused tgt-histogram (round-6, verified
// useful). GELU LDS table REVERTED (13.3M bank conflicts, -24us). ----------
__global__ __launch_bounds__(256) void edge_mlp_mfma(const float* __restrict__ edge_attr,
                                                     const float* __restrict__ e_w1,
                                                     const float* __restrict__ e_b1,
                                                     const float* __restrict__ e_w2,
                                                     const float* __restrict__ e_b2,
                                                     float* __restrict__ scores,
                                                     const int* __restrict__ tgt,
                                                     int* __restrict__ cnt) {
    __shared__ __align__(16) short w1s[256 * 8];
    __shared__ __align__(16) float b1s[256];
    __shared__ __align__(16) float ea_s[256 * 6];

    int tid = threadIdx.x;
    int lane = tid & 63, wv = tid >> 6;
    int l16 = lane & 15, quad = lane >> 4;

    // fused histogram: one edge per thread (hidden under staging/compute)
    atomicAdd(&cnt[tgt[blockIdx.x * 256 + tid]], 1);

    // stage w1 (bf16, padded to 8), b1, edge_attr (coalesced)
    {
        int n = tid;
#pragma unroll
        for (int k = 0; k < 6; ++k) w1s[n * 8 + k] = f2b(e_w1[n * 6 + k]);
        w1s[n * 8 + 6] = 0; w1s[n * 8 + 7] = 0;
        b1s[n] = e_b1[n];
    }
    {
        size_t base = (size_t)blockIdx.x * (256 * 6);
#pragma unroll
        for (int it = 0; it < 6; ++it) {
            int i = tid + it * 256;
            ea_s[i] = edge_attr[base + i];
        }
    }

    // w2 B-fragments with hidden-permutation applied to column index
    bf16x8 w2f[8];
#pragma unroll
    for (int c = 0; c < 8; ++c) {
#pragma unroll
        for (int j = 0; j < 8; ++j) {
            int col = c * 32 + ((j & 4) ? 16 : 0) + quad * 4 + (j & 3);
            w2f[c][j] = f2b(e_w2[l16 * 256 + col]);
        }
    }
    float b2r = e_b2[l16];
    __syncthreads();

    // B-fragments for all 4 edge-groups (only quad==0 carries k=0..5)
    bf16x8 bfr[4];
#pragma unroll
    for (int g = 0; g < 4; ++g) {
        bfr[g] = (bf16x8){0, 0, 0, 0, 0, 0, 0, 0};
        if (quad == 0) {
            const float* p = &ea_s[(wv * 64 + g * 16 + l16) * 6];
#pragma unroll
            for (int j = 0; j < 6; ++j) bfr[g][j] = f2b(p[j]);
        }
    }

    f32x4 acc[4];
#pragma unroll
    for (int g = 0; g < 4; ++g) acc[g] = (f32x4){0.f, 0.f, 0.f, 0.f};

#pragma unroll
    for (int c2 = 0; c2 < 8; ++c2) {
        bf16x8 af0 = (bf16x8){0, 0, 0, 0, 0, 0, 0, 0};
        bf16x8 af1 = (bf16x8){0, 0, 0, 0, 0, 0, 0, 0};
        if (quad == 0) {
            af0 = *(bf16x8*)&w1s[((2 * c2) * 16 + l16) * 8];
            af1 = *(bf16x8*)&w1s[((2 * c2 + 1) * 16 + l16) * 8];
        }
        f32x4 bb0 = *(const f32x4*)&b1s[(2 * c2) * 16 + quad * 4];
        f32x4 bb1 = *(const f32x4*)&b1s[(2 * c2 + 1) * 16 + quad * 4];
#pragma unroll
        for (int g = 0; g < 4; ++g) {
            f32x4 cc0 = MFMA16(af0, bfr[g], bb0);   // bias via C-in
            f32x4 cc1 = MFMA16(af1, bfr[g], bb1);
            unsigned pw[4];
            pw[0] = cvt_pk_bf16(gelu_f(cc0[0]), gelu_f(cc0[1]));
            pw[1] = cvt_pk_bf16(gelu_f(cc0[2]), gelu_f(cc0[3]));
            pw[2] = cvt_pk_bf16(gelu_f(cc1[0]), gelu_f(cc1[1]));
            pw[3] = cvt_pk_bf16(gelu_f(cc1[2]), gelu_f(cc1[3]));
            bf16x8 pa = *reinterpret_cast<bf16x8*>(pw);
            acc[g] = MFMA16(pa, w2f[c2], acc[g]);
        }
    }

    long eblk = (long)blockIdx.x * 256 + wv * 64;
#pragma unroll
    for (int g = 0; g < 4; ++g) {
        long e0 = eblk + g * 16;
#pragma unroll
        for (int rr = 0; rr < 4; ++rr)
            scores[(size_t)(e0 + quad * 4 + rr) * 16 + l16] = acc[g][rr] + b2r;
    }
}

// ---------- node_agg3: wave-per-node fused softmax + aggregation ----------
// 4 nodes per 256-block, one wave each, ZERO __syncthreads (all LDS traffic is
// wave-internal; DS ops are FIFO-ordered within a wave). Fast path deg<=64:
// lane k holds edge k's 16 scores in regs; channel reduce via stride-65 LDS
// transpose (conflict-free) with k=4j+q interleave (trip=ceil(deg/4)) + 2-step
// shfl_xor butterfly. Rare path deg>64: wave-local chunked online softmax.
__global__ __launch_bounds__(256) void node_agg3(const int* __restrict__ sorted_eid,
                                                 const int* __restrict__ offs,
                                                 const int* __restrict__ srcp,
                                                 const float* __restrict__ scores,
                                                 const short* __restrict__ Vb,
                                                 const float* __restrict__ betap,
                                                 short* __restrict__ accumb,
                                                 float* __restrict__ attn_out) {
    __shared__ __align__(16) float scr_all[4][16 * 65];  // transposed scores; later w[k*8+h]
    __shared__ __align__(16) float ms_all[4][32];        // m[0..15], rcp(s)[16..31]
    __shared__ int src_all[4][64];

    int tid = threadIdx.x;
    int wv = tid >> 6, lane = tid & 63;
    int n = blockIdx.x * 4 + wv;
    float* scr = scr_all[wv];
    float* ms  = ms_all[wv];
    int* srcs  = src_all[wv];

    int beg = offs[n];
    int deg = offs[n + 1] - beg;
    int c16 = lane & 15, q4 = lane >> 4;
    int d0 = lane * 4, hh = lane >> 3;

    if (deg == 0) {
        bf16x4 z = (bf16x4){0, 0, 0, 0};
        *(bf16x4*)&accumb[(size_t)n * 256 + d0] = z;
        return;
    }
    float beta = *betap;

    if (deg <= 64) {
        int k = lane;
        int eid = 0, src = 0;
        float sc[16];
        if (k < deg) {
            eid = sorted_eid[beg + k];
            src = srcp[eid];
            const f32x4* sp = (const f32x4*)&scores[(size_t)eid * 16];
            f32x4 s0 = sp[0], s1 = sp[1], s2 = sp[2], s3 = sp[3];
            sc[0]=s0[0]; sc[1]=s0[1]; sc[2]=s0[2]; sc[3]=s0[3];
            sc[4]=s1[0]; sc[5]=s1[1]; sc[6]=s1[2]; sc[7]=s1[3];
            sc[8]=s2[0]; sc[9]=s2[1]; sc[10]=s2[2]; sc[11]=s2[3];
            sc[12]=s3[0]; sc[13]=s3[1]; sc[14]=s3[2]; sc[15]=s3[3];
        } else {
#pragma unroll
            for (int c = 0; c < 16; ++c) sc[c] = -INFINITY;
        }
        srcs[k] = src;
        // transpose write: scr[c][k], stride 65 (conflict-free: bank = (c+k)%32)
#pragma unroll
        for (int c = 0; c < 16; ++c) scr[c * 65 + k] = sc[c];

        // channel-lane reduce: lane (c16, q4) covers edges k = 4j + q4
        float mloc = -INFINITY;
        for (int j = 0; 4 * j < deg; ++j)
            mloc = fmaxf(mloc, scr[c16 * 65 + 4 * j + q4]);
        mloc = fmaxf(mloc, __shfl_xor(mloc, 16));
        mloc = fmaxf(mloc, __shfl_xor(mloc, 32));
        float sloc = 0.f;
        for (int j = 0; 4 * j < deg; ++j)
            sloc += __expf(scr[c16 * 65 + 4 * j + q4] - mloc);
        sloc += __shfl_xor(sloc, 16);
        sloc += __shfl_xor(sloc, 32);
        if (lane < 16) {
            ms[c16] = mloc;
            ms[16 + c16] = __builtin_amdgcn_rcpf(sloc);
        }

        // weights from register scores + broadcast m/rs
        if (k < deg) {
            float w[8];
#pragma unroll
            for (int h = 0; h < 8; ++h) {
                f32x2 mp = *(const f32x2*)&ms[2 * h];
                f32x2 rp = *(const f32x2*)&ms[16 + 2 * h];
                w[h] = __expf(sc[2 * h] - mp[0]) * rp[0]
                     - beta * __expf(sc[2 * h + 1] - mp[1]) * rp[1];
            }
            f32x4 w0 = (f32x4){w[0], w[1], w[2], w[3]};
            f32x4 w1 = (f32x4){w[4], w[5], w[6], w[7]};
            *(f32x4*)&attn_out[(size_t)eid * 8]     = w0;
            *(f32x4*)&attn_out[(size_t)eid * 8 + 4] = w1;
            *(f32x4*)&scr[k * 8]     = w0;   // overwrites transposed scores (done)
            *(f32x4*)&scr[k * 8 + 4] = w1;
        }

        // V accumulate: lane d0..d0+3, head hh; coalesced 512B row per k
        float a0 = 0.f, a1 = 0.f, a2 = 0.f, a3 = 0.f;
        for (int kk = 0; kk < deg; ++kk) {
            float wk = scr[kk * 8 + hh];
            int sk = srcs[kk];
            bf16x4 v = *(const bf16x4*)&Vb[(size_t)sk * 256 + d0];
            a0 += wk * b2f(v[0]);
            a1 += wk * b2f(v[1]);
            a2 += wk * b2f(v[2]);
            a3 += wk * b2f(v[3]);
        }
        bf16x4 r;
        r[0] = f2b(a0); r[1] = f2b(a1); r[2] = f2b(a2); r[3] = f2b(a3);
        *(bf16x4*)&accumb[(size_t)n * 256 + d0] = r;
        return;
    }

    // ---- rare path (deg > 64): wave-local chunked online softmax ----
    float m_run = -INFINITY, s_run = 0.f;
    for (int base = 0; base < deg; base += 64) {
        int k = base + lane;
        float sc[16];
        if (k < deg) {
            int eid = sorted_eid[beg + k];
            const f32x4* sp = (const f32x4*)&scores[(size_t)eid * 16];
            f32x4 s0 = sp[0], s1 = sp[1], s2 = sp[2], s3 = sp[3];
            sc[0]=s0[0]; sc[1]=s0[1]; sc[2]=s0[2]; sc[3]=s0[3];
            sc[4]=s1[0]; sc[5]=s1[1]; sc[6]=s1[2]; sc[7]=s1[3];
            sc[8]=s2[0]; sc[9]=s2[1]; sc[10]=s2[2]; sc[11]=s2[3];
            sc[12]=s3[0]; sc[13]=s3[1]; sc[14]=s3[2]; sc[15]=s3[3];
        } else {
#pragma unroll
            for (int c = 0; c < 16; ++c) sc[c] = -INFINITY;
        }
#pragma unroll
        for (int c = 0; c < 16; ++c) scr[c * 65 + lane] = sc[c];
        float mc = -INFINITY;
#pragma unroll
        for (int j = 0; j < 16; ++j)
            mc = fmaxf(mc, scr[c16 * 65 + 4 * j + q4]);
        mc = fmaxf(mc, __shfl_xor(mc, 16));
        mc = fmaxf(mc, __shfl_xor(mc, 32));
        float m_new = fmaxf(m_run, mc);
        float ssum = 0.f;
#pragma unroll
        for (int j = 0; j < 16; ++j)
            ssum += __expf(scr[c16 * 65 + 4 * j + q4] - m_new);
        ssum += __shfl_xor(ssum, 16);
        ssum += __shfl_xor(ssum, 32);
        s_run = s_run * __expf(m_run - m_new) + ssum;
        m_run = m_new;
    }
    if (lane < 16) {
        ms[c16] = m_run;
        ms[16 + c16] = __builtin_amdgcn_rcpf(s_run);
    }

    float a0 = 0.f, a1 = 0.f, a2 = 0.f, a3 = 0.f;
    for (int base = 0; base < deg; base += 64) {
        int k = base + lane;
        int cn = min(64, deg - base);
        int src = 0;
        if (lane < cn) {
            int eid = sorted_eid[beg + k];
            src = srcp[eid];
            const f32x4* sp = (const f32x4*)&scores[(size_t)eid * 16];
            f32x4 s0 = sp[0], s1 = sp[1], s2 = sp[2], s3 = sp[3];
            float sc[16];
            sc[0]=s0[0]; sc[1]=s0[1]; sc[2]=s0[2]; sc[3]=s0[3];
            sc[4]=s1[0]; sc[5]=s1[1]; sc[6]=s1[2]; sc[7]=s1[3];
            sc[8]=s2[0]; sc[9]=s2[1]; sc[10]=s2[2]; sc[11]=s2[3];
            sc[12]=s3[0]; sc[13]=s3[1]; sc[14]=s3[2]; sc[15]=s3[3];
            float w[8];
#pragma unroll
            for (int h = 0; h < 8; ++h) {
                f32x2 mp = *(const f32x2*)&ms[2 * h];
                f32x2 rp = *(const f32x2*)&ms[16 + 2 * h];
                w[h] = __expf(sc[2 * h] - mp[0]) * rp[0]
                     - beta * __expf(sc[2 * h + 1] - mp[1]) * rp[1];
            }
            f32x4 w0 = (f32x4){w[0], w[1], w[2], w[3]};
            f32x4 w1 = (f32x4){w[4], w[5], w[6], w[7]};
            *(f32x4*)&attn_out[(size_t)eid * 8]     = w0;
            *(f32x4*)&attn_out[(size_t)eid * 8 + 4] = w1;
            *(f32x4*)&scr[lane * 8]     = w0;
            *(f32x4*)&scr[lane * 8 + 4] = w1;
        }
        srcs[lane] = src;
        for (int kk = 0; kk < cn; ++kk) {
            float wk = scr[kk * 8 + hh];
            int sk = srcs[kk];
            bf16x4 v = *(const bf16x4*)&Vb[(size_t)sk * 256 + d0];
            a0 += wk * b2f(v[0]);
            a1 += wk * b2f(v[1]);
            a2 += wk * b2f(v[2]);
            a3 += wk * b2f(v[3]);
        }
    }
    bf16x4 r;
    r[0] = f2b(a0); r[1] = f2b(a1); r[2] = f2b(a2); r[3] = f2b(a3);
    *(bf16x4*)&accumb[(size_t)n * 256 + d0] = r;
}

extern "C" void kernel_launch(void* const* d_in, const int* in_sizes, int n_in,
                              void* d_out, int out_size, void* d_ws, size_t ws_size,
                              hipStream_t stream) {
    const float* x         = (const float*)d_in[0];
    const float* edge_attr = (const float*)d_in[1];
    const float* v_w       = (const float*)d_in[2];
    const float* out_w     = (const float*)d_in[3];
    const float* e_w1      = (const float*)d_in[4];
    const float* e_b1      = (const float*)d_in[5];
    const float* e_w2      = (const float*)d_in[6];
    const float* e_b2      = (const float*)d_in[7];
    const float* lq        = (const float*)d_in[8];
    const float* lk        = (const float*)d_in[9];
    const int*   ei        = (const int*)d_in[10];
    const int* srcp = ei;
    const int* tgtp = ei + N_EDGES;

    float* out = (float*)d_out;
    float* attn_out = out + (size_t)N_NODES * 256;
    float* beta_out = attn_out + (size_t)N_EDGES * 8;

    // workspace layout
    short* Vb     = (short*)d_ws;                              // N*256 bf16
    float* scores = (float*)(Vb + (size_t)N_NODES * 256);      // E*16 f32
    short* accumb = (short*)(scores + (size_t)N_EDGES * 16);   // N*256 bf16
    int*   cnt    = (int*)(accumb + (size_t)N_NODES * 256);
    int*   offs   = cnt + N_NODES;
    int*   cursor = offs + N_NODES + 1;
    int*   partials = cursor + N_NODES;
    int*   sorted_eid = partials + 256;
    float* betap  = (float*)(sorted_eid + N_EDGES);

    const int NB = (N_NODES + 255) / 256;

    hipMemsetAsync(cnt, 0, N_NODES * sizeof(int), stream);

    // edge MLP -> scores (+ fused tgt histogram)
    edge_mlp_mfma<<<N_EDGES / 256, 256, 0, stream>>>(edge_attr, e_w1, e_b1, e_w2, e_b2,
                                                     scores, tgtp, cnt);

    scan1<<<NB, 256, 0, stream>>>(cnt, offs, partials, N_NODES);
    scan2<<<1, 256, 0, stream>>>(partials, NB, lq, lk, betap, beta_out);
    scan3<<<NB, 256, 0, stream>>>(offs, partials, cursor, N_NODES);
    scatter_eid<<<(N_EDGES + 255) / 256, 256, 0, stream>>>(tgtp, cursor, sorted_eid);

    // V(bf16) = x @ v_w.T
    gemm_mfma_t<false, true><<<dim3((N_NODES + 127) / 128, 4), 256, 0, stream>>>(
        x, v_w, Vb, N_NODES);

    // fused softmax + aggregation (wave per node)
    node_agg3<<<N_NODES / 4, 256, 0, stream>>>(sorted_eid, offs, srcp, scores, Vb, betap,
                                               accumb, attn_out);

    // out = accum(bf16) @ out_w.T
    gemm_mfma_t<true, false><<<dim3((N_NODES + 127) / 128, 4), 256, 0, stream>>>(
        accumb, out_w, out, N_NODES);
}

// Round 8
// 421.033 us; speedup vs baseline: 1.0913x; 1.0913x over previous
//
#include <hip/hip_runtime.h>
#include <hip/hip_bf16.h>
#include <math.h>

#define N_NODES 50000
#define N_EDGES 800000
#define DIM 256
#define HEADS 8
#define LAMBDA_INIT 0.63212055882855767f

using bf16x8 = __attribute__((ext_vector_type(8))) short;
using bf16x4 = __attribute__((ext_vector_type(4))) short;
using f32x4  = __attribute__((ext_vector_type(4))) float;
using f32x2  = __attribute__((ext_vector_type(2))) float;
#define MFMA16(a, b, c) __builtin_amdgcn_mfma_f32_16x16x32_bf16(a, b, c, 0, 0, 0)

__device__ __forceinline__ short f2b(float f) {
    __hip_bfloat16 h = __float2bfloat16(f);
    return *reinterpret_cast<short*>(&h);
}
__device__ __forceinline__ float b2f(short s) {
    unsigned u = ((unsigned)(unsigned short)s) << 16;
    return __uint_as_float(u);
}
// pack 2 f32 -> 2 bf16 (RNE), single instruction
__device__ __forceinline__ unsigned cvt_pk_bf16(float a, float b) {
    unsigned r;
    asm("v_cvt_pk_bf16_f32 %0, %1, %2" : "=v"(r) : "v"(a), "v"(b));
    return r;
}

// GELU, relu-form: gelu(x) = max(x,0) - |x| * q'(t) * exp(-x^2/2),
// q' = 0.5*(a1 t + a2 t^2 + a3 t^3), t = 1/(1+0.47047*|x|/sqrt2)
// (A&S 7.1.25, |erf err| <= 2.5e-5 -- far below bf16 quantization)
__device__ __forceinline__ float gelu_f(float x) {
    float az = 0.70710678118654752f * fabsf(x);
    float t  = __builtin_amdgcn_rcpf(fmaf(0.47047f, az, 1.f));
    float q  = fmaf(fmaf(0.3739278f, t, -0.0479399f), t, 0.1740121f) * t;
    float E  = __expf(-az * az);
    return fmaf(-q * E, fabsf(x), fmaxf(x, 0.f));
}

// ---------- prefix-sum pipeline over per-node counts ----------
__global__ __launch_bounds__(256) void scan1(const int* __restrict__ cnt,
                                             int* __restrict__ offs,
                                             int* __restrict__ partials, int n) {
    __shared__ int sh[256];
    int i = blockIdx.x * 256 + threadIdx.x;
    int v = (i < n) ? cnt[i] : 0;
    sh[threadIdx.x] = v;
    __syncthreads();
    for (int s = 1; s < 256; s <<= 1) {
        int add = (threadIdx.x >= s) ? sh[threadIdx.x - s] : 0;
        __syncthreads();
        sh[threadIdx.x] += add;
        __syncthreads();
    }
    if (i < n) offs[i] = sh[threadIdx.x] - v;
    if (threadIdx.x == 255) partials[blockIdx.x] = sh[255];
}

// scan of block partials + beta computation (fused; both tiny, single block)
__global__ __launch_bounds__(256) void scan2(int* __restrict__ partials, int nb,
                                             const float* __restrict__ lq,
                                             const float* __restrict__ lk,
                                             float* __restrict__ beta_ws,
                                             float* __restrict__ beta_out) {
    __shared__ int sh[256];
    __shared__ float redb[128];
    int tid = threadIdx.x;
    int v = (tid < nb) ? partials[tid] : 0;
    sh[tid] = v;
    __syncthreads();
    for (int s = 1; s < 256; s <<= 1) {
        int add = (tid >= s) ? sh[tid - s] : 0;
        __syncthreads();
        sh[tid] += add;
        __syncthreads();
    }
    if (tid < nb) partials[tid] = sh[tid] - v;

    // ---- beta ----
    if (tid < 128) {
        float b = 0.f;
        for (int i = tid; i < 100; i += 128) b += lq[i] * lk[i];
        redb[tid] = b;
    }
    __syncthreads();
    for (int s = 64; s > 0; s >>= 1) {
        if (tid < s) redb[tid] += redb[tid + s];
        __syncthreads();
    }
    if (tid == 0) {
        float l1 = expf(redb[0]);
        float b = 1.f / (1.f + expf(-l1 * LAMBDA_INIT));
        *beta_ws = b;
        *beta_out = b;
    }
}

__global__ __launch_bounds__(256) void scan3(int* __restrict__ offs,
                                             const int* __restrict__ partials,
                                             int* __restrict__ cursor, int n) {
    int i = blockIdx.x * 256 + threadIdx.x;
    if (i < n) {
        int o = offs[i] + partials[blockIdx.x];
        offs[i] = o;
        cursor[i] = o;
    }
    if (i == 0) offs[n] = N_EDGES;
}

// ---------- bf16-MFMA GEMM: C[m,n] = sum_k A[m,k] * W[n,k] ----------
// Optionally fuses the tgt-histogram (2 atomicAdds/thread, hidden under
// compute) so the counting-sort needs no standalone hist kernel.
template <bool ABF, bool CBF>
__global__ __launch_bounds__(256) void gemm_mfma_t(const void* __restrict__ Av,
                                                   const float* __restrict__ W,
                                                   void* __restrict__ Cv, int M,
                                                   const int* __restrict__ hist_tgt,
                                                   int* __restrict__ hist_cnt) {
    __shared__ __align__(16) short As[128 * 40];
    __shared__ __align__(16) short Ws[64 * 40];
    int tid = threadIdx.x;
    int lane = tid & 63, wv = tid >> 6;
    int l16 = lane & 15, quad = lane >> 4;
    int bm = blockIdx.x * 128, bn = blockIdx.y * 64;

    if (hist_tgt) {
        int gtid = (blockIdx.x * 4 + blockIdx.y) * 256 + tid;
        int e0 = gtid * 2;
        if (e0 < N_EDGES)     atomicAdd(&hist_cnt[hist_tgt[e0]], 1);
        if (e0 + 1 < N_EDGES) atomicAdd(&hist_cnt[hist_tgt[e0 + 1]], 1);
    }

    f32x4 acc[2][4];
#pragma unroll
    for (int mt = 0; mt < 2; ++mt)
#pragma unroll
        for (int nt = 0; nt < 4; ++nt) acc[mt][nt] = (f32x4){0.f, 0.f, 0.f, 0.f};

    int r = tid >> 1, hf = tid & 1;
    int rw = (tid & 127) >> 1, hw = tid & 1;

    for (int k0 = 0; k0 < 256; k0 += 32) {
        {
            int m = bm + r;
            bf16x8 p0, p1;
            if (ABF) {
                if (m < M) {
                    const bf16x8* ap =
                        (const bf16x8*)&((const short*)Av)[(size_t)m * 256 + k0 + hf * 16];
                    p0 = ap[0]; p1 = ap[1];
                } else {
                    p0 = (bf16x8){0,0,0,0,0,0,0,0}; p1 = p0;
                }
            } else {
                float4 f0, f1, f2, f3;
                if (m < M) {
                    const float4* ap =
                        (const float4*)&((const float*)Av)[(size_t)m * 256 + k0 + hf * 16];
                    f0 = ap[0]; f1 = ap[1]; f2 = ap[2]; f3 = ap[3];
                } else {
                    f0 = f1 = f2 = f3 = make_float4(0.f, 0.f, 0.f, 0.f);
                }
                p0[0]=f2b(f0.x); p0[1]=f2b(f0.y); p0[2]=f2b(f0.z); p0[3]=f2b(f0.w);
                p0[4]=f2b(f1.x); p0[5]=f2b(f1.y); p0[6]=f2b(f1.z); p0[7]=f2b(f1.w);
                p1[0]=f2b(f2.x); p1[1]=f2b(f2.y); p1[2]=f2b(f2.z); p1[3]=f2b(f2.w);
                p1[4]=f2b(f3.x); p1[5]=f2b(f3.y); p1[6]=f2b(f3.z); p1[7]=f2b(f3.w);
            }
            *(bf16x8*)&As[r * 40 + hf * 16]     = p0;
            *(bf16x8*)&As[r * 40 + hf * 16 + 8] = p1;
        }
        if (tid < 128) {
            const float4* wp = (const float4*)&W[(size_t)(bn + rw) * 256 + k0 + hw * 16];
            float4 f0 = wp[0], f1 = wp[1], f2 = wp[2], f3 = wp[3];
            bf16x8 p0, p1;
            p0[0]=f2b(f0.x); p0[1]=f2b(f0.y); p0[2]=f2b(f0.z); p0[3]=f2b(f0.w);
            p0[4]=f2b(f1.x); p0[5]=f2b(f1.y); p0[6]=f2b(f1.z); p0[7]=f2b(f1.w);
            p1[0]=f2b(f2.x); p1[1]=f2b(f2.y); p1[2]=f2b(f2.z); p1[3]=f2b(f2.w);
            p1[4]=f2b(f3.x); p1[5]=f2b(f3.y); p1[6]=f2b(f3.z); p1[7]=f2b(f3.w);
            *(bf16x8*)&Ws[rw * 40 + hw * 16]     = p0;
            *(bf16x8*)&Ws[rw * 40 + hw * 16 + 8] = p1;
        }
        __syncthreads();
#pragma unroll
        for (int mt = 0; mt < 2; ++mt) {
            bf16x8 afr = *(bf16x8*)&As[(wv * 32 + mt * 16 + l16) * 40 + quad * 8];
#pragma unroll
            for (int nt = 0; nt < 4; ++nt) {
                bf16x8 bfr = *(bf16x8*)&Ws[(nt * 16 + l16) * 40 + quad * 8];
                acc[mt][nt] = MFMA16(afr, bfr, acc[mt][nt]);
            }
        }
        __syncthreads();
    }
#pragma unroll
    for (int mt = 0; mt < 2; ++mt) {
#pragma unroll
        for (int rr = 0; rr < 4; ++rr) {
            int m = bm + wv * 32 + mt * 16 + quad * 4 + rr;
            if (m < M) {
#pragma unroll
                for (int nt = 0; nt < 4; ++nt) {
                    if (CBF)
                        ((short*)Cv)[(size_t)m * 256 + bn + nt * 16 + l16] =
                            f2b(acc[mt][nt][rr]);
                    else
                        ((float*)Cv)[(size_t)m * 256 + bn + nt * 16 + l16] =
                            acc[mt][nt][rr];
                }
            }
        }
    }
}

// ---------- edge MLP v7: v6 compute + DIRECT SORTED-SLOT OUTPUT ----------
// Each edge claims its slot in the tgt-sorted order via atomicAdd(cursor[tgt])
// (cursor pre-initialized to offs by scan3). Scores, src and eid are written
// slot-indexed, so node_agg reads are fully coalesced and scatter_eid dies.
__global__ __launch_bounds__(256) void edge_mlp_mfma(const float* __restrict__ edge_attr,
                                                     const float* __restrict__ e_w1,
                                                     const float* __restrict__ e_b1,
                                                     const float* __restrict__ e_w2,
                                                     const float* __restrict__ e_b2,
                                                     const int* __restrict__ tgt,
                                                     const int* __restrict__ srcp,
                                                     int* __restrict__ cursor,
                                                     float* __restrict__ sorted_sc,
                                                     int* __restrict__ slot_eid,
                                                     int* __restrict__ slot_src) {
    __shared__ __align__(16) short w1s[256 * 8];
    __shared__ __align__(16) float b1s[256];
    __shared__ __align__(16) float ea_s[256 * 6];
    __shared__ int slot_lds[4][64];

    int tid = threadIdx.x;
    int lane = tid & 63, wv = tid >> 6;
    int l16 = lane & 15, quad = lane >> 4;
    long eblk = (long)blockIdx.x * 256 + wv * 64;

    // slot assignment: lane k claims the slot for edge eblk+k (wave-local LDS)
    {
        int e = (int)(eblk + lane);
        int p = atomicAdd(&cursor[tgt[e]], 1);
        slot_lds[wv][lane] = p;
        slot_eid[p] = e;
        slot_src[p] = srcp[e];
    }

    // stage w1 (bf16, padded to 8), b1, edge_attr (coalesced)
    {
        int n = tid;
#pragma unroll
        for (int k = 0; k < 6; ++k) w1s[n * 8 + k] = f2b(e_w1[n * 6 + k]);
        w1s[n * 8 + 6] = 0; w1s[n * 8 + 7] = 0;
        b1s[n] = e_b1[n];
    }
    {
        size_t base = (size_t)blockIdx.x * (256 * 6);
#pragma unroll
        for (int it = 0; it < 6; ++it) {
            int i = tid + it * 256;
            ea_s[i] = edge_attr[base + i];
        }
    }

    // w2 B-fragments with hidden-permutation applied to column index
    bf16x8 w2f[8];
#pragma unroll
    for (int c = 0; c < 8; ++c) {
#pragma unroll
        for (int j = 0; j < 8; ++j) {
            int col = c * 32 + ((j & 4) ? 16 : 0) + quad * 4 + (j & 3);
            w2f[c][j] = f2b(e_w2[l16 * 256 + col]);
        }
    }
    float b2r = e_b2[l16];
    __syncthreads();

    // B-fragments for all 4 edge-groups (only quad==0 carries k=0..5)
    bf16x8 bfr[4];
#pragma unroll
    for (int g = 0; g < 4; ++g) {
        bfr[g] = (bf16x8){0, 0, 0, 0, 0, 0, 0, 0};
        if (quad == 0) {
            const float* p = &ea_s[(wv * 64 + g * 16 + l16) * 6];
#pragma unroll
            for (int j = 0; j < 6; ++j) bfr[g][j] = f2b(p[j]);
        }
    }

    f32x4 acc[4];
#pragma unroll
    for (int g = 0; g < 4; ++g) acc[g] = (f32x4){0.f, 0.f, 0.f, 0.f};

#pragma unroll
    for (int c2 = 0; c2 < 8; ++c2) {
        bf16x8 af0 = (bf16x8){0, 0, 0, 0, 0, 0, 0, 0};
        bf16x8 af1 = (bf16x8){0, 0, 0, 0, 0, 0, 0, 0};
        if (quad == 0) {
            af0 = *(bf16x8*)&w1s[((2 * c2) * 16 + l16) * 8];
            af1 = *(bf16x8*)&w1s[((2 * c2 + 1) * 16 + l16) * 8];
        }
        f32x4 bb0 = *(const f32x4*)&b1s[(2 * c2) * 16 + quad * 4];
        f32x4 bb1 = *(const f32x4*)&b1s[(2 * c2 + 1) * 16 + quad * 4];
#pragma unroll
        for (int g = 0; g < 4; ++g) {
            f32x4 cc0 = MFMA16(af0, bfr[g], bb0);   // bias via C-in
            f32x4 cc1 = MFMA16(af1, bfr[g], bb1);
            unsigned pw[4];
            pw[0] = cvt_pk_bf16(gelu_f(cc0[0]), gelu_f(cc0[1]));
            pw[1] = cvt_pk_bf16(gelu_f(cc0[2]), gelu_f(cc0[3]));
            pw[2] = cvt_pk_bf16(gelu_f(cc1[0]), gelu_f(cc1[1]));
            pw[3] = cvt_pk_bf16(gelu_f(cc1[2]), gelu_f(cc1[3]));
            bf16x8 pa = *reinterpret_cast<bf16x8*>(pw);
            acc[g] = MFMA16(pa, w2f[c2], acc[g]);
        }
    }

    // slot-indexed stores (16 lanes x 64B per edge)
#pragma unroll
    for (int g = 0; g < 4; ++g) {
#pragma unroll
        for (int rr = 0; rr < 4; ++rr) {
            int p = slot_lds[wv][g * 16 + quad * 4 + rr];
            sorted_sc[(size_t)p * 16 + l16] = acc[g][rr] + b2r;
        }
    }
}

// ---------- node_agg4: wave-per-node, ALL slot-indexed coalesced loads ----------
// (scores/src/eid pre-sorted by edge_mlp; no dependent gathers remain)
__global__ __launch_bounds__(256) void node_agg4(const int* __restrict__ slot_eid,
                                                 const int* __restrict__ offs,
                                                 const int* __restrict__ slot_src,
                                                 const float* __restrict__ sorted_sc,
                                                 const short* __restrict__ Vb,
                                                 const float* __restrict__ betap,
                                                 short* __restrict__ accumb,
                                                 float* __restrict__ attn_out) {
    __shared__ __align__(16) float scr_all[4][16 * 65];  // transposed scores; later w[k*8+h]
    __shared__ __align__(16) float ms_all[4][32];        // m[0..15], rcp(s)[16..31]
    __shared__ int src_all[4][64];

    int tid = threadIdx.x;
    int wv = tid >> 6, lane = tid & 63;
    int n = blockIdx.x * 4 + wv;
    float* scr = scr_all[wv];
    float* ms  = ms_all[wv];
    int* srcs  = src_all[wv];

    int beg = offs[n];
    int deg = offs[n + 1] - beg;
    int c16 = lane & 15, q4 = lane >> 4;
    int d0 = lane * 4, hh = lane >> 3;

    if (deg == 0) {
        bf16x4 z = (bf16x4){0, 0, 0, 0};
        *(bf16x4*)&accumb[(size_t)n * 256 + d0] = z;
        return;
    }
    float beta = *betap;

    if (deg <= 64) {
        int k = lane;
        int eid = 0, src = 0;
        float sc[16];
        if (k < deg) {
            int slot = beg + k;
            eid = slot_eid[slot];
            src = slot_src[slot];
            const f32x4* sp = (const f32x4*)&sorted_sc[(size_t)slot * 16];
            f32x4 s0 = sp[0], s1 = sp[1], s2 = sp[2], s3 = sp[3];
            sc[0]=s0[0]; sc[1]=s0[1]; sc[2]=s0[2]; sc[3]=s0[3];
            sc[4]=s1[0]; sc[5]=s1[1]; sc[6]=s1[2]; sc[7]=s1[3];
            sc[8]=s2[0]; sc[9]=s2[1]; sc[10]=s2[2]; sc[11]=s2[3];
            sc[12]=s3[0]; sc[13]=s3[1]; sc[14]=s3[2]; sc[15]=s3[3];
        } else {
#pragma unroll
            for (int c = 0; c < 16; ++c) sc[c] = -INFINITY;
        }
        srcs[k] = src;
        // transpose write: scr[c][k], stride 65 (conflict-free: bank = (c+k)%32)
#pragma unroll
        for (int c = 0; c < 16; ++c) scr[c * 65 + k] = sc[c];

        // channel-lane reduce: lane (c16, q4) covers edges k = 4j + q4
        float mloc = -INFINITY;
        for (int j = 0; 4 * j < deg; ++j)
            mloc = fmaxf(mloc, scr[c16 * 65 + 4 * j + q4]);
        mloc = fmaxf(mloc, __shfl_xor(mloc, 16));
        mloc = fmaxf(mloc, __shfl_xor(mloc, 32));
        float sloc = 0.f;
        for (int j = 0; 4 * j < deg; ++j)
            sloc += __expf(scr[c16 * 65 + 4 * j + q4] - mloc);
        sloc += __shfl_xor(sloc, 16);
        sloc += __shfl_xor(sloc, 32);
        if (lane < 16) {
            ms[c16] = mloc;
            ms[16 + c16] = __builtin_amdgcn_rcpf(sloc);
        }

        // weights from register scores + broadcast m/rs
        if (k < deg) {
            float w[8];
#pragma unroll
            for (int h = 0; h < 8; ++h) {
                f32x2 mp = *(const f32x2*)&ms[2 * h];
                f32x2 rp = *(const f32x2*)&ms[16 + 2 * h];
                w[h] = __expf(sc[2 * h] - mp[0]) * rp[0]
                     - beta * __expf(sc[2 * h + 1] - mp[1]) * rp[1];
            }
            f32x4 w0 = (f32x4){w[0], w[1], w[2], w[3]};
            f32x4 w1 = (f32x4){w[4], w[5], w[6], w[7]};
            *(f32x4*)&attn_out[(size_t)eid * 8]     = w0;
            *(f32x4*)&attn_out[(size_t)eid * 8 + 4] = w1;
            *(f32x4*)&scr[k * 8]     = w0;   // overwrites transposed scores (done)
            *(f32x4*)&scr[k * 8 + 4] = w1;
        }

        // V accumulate: lane d0..d0+3, head hh; coalesced 512B row per k
        float a0 = 0.f, a1 = 0.f, a2 = 0.f, a3 = 0.f;
        for (int kk = 0; kk < deg; ++kk) {
            float wk = scr[kk * 8 + hh];
            int sk = srcs[kk];
            bf16x4 v = *(const bf16x4*)&Vb[(size_t)sk * 256 + d0];
            a0 += wk * b2f(v[0]);
            a1 += wk * b2f(v[1]);
            a2 += wk * b2f(v[2]);
            a3 += wk * b2f(v[3]);
        }
        bf16x4 r;
        r[0] = f2b(a0); r[1] = f2b(a1); r[2] = f2b(a2); r[3] = f2b(a3);
        *(bf16x4*)&accumb[(size_t)n * 256 + d0] = r;
        return;
    }

    // ---- rare path (deg > 64): wave-local chunked online softmax ----
    float m_run = -INFINITY, s_run = 0.f;
    for (int base = 0; base < deg; base += 64) {
        int k = base + lane;
        float sc[16];
        if (k < deg) {
            const f32x4* sp = (const f32x4*)&sorted_sc[(size_t)(beg + k) * 16];
            f32x4 s0 = sp[0], s1 = sp[1], s2 = sp[2], s3 = sp[3];
            sc[0]=s0[0]; sc[1]=s0[1]; sc[2]=s0[2]; sc[3]=s0[3];
            sc[4]=s1[0]; sc[5]=s1[1]; sc[6]=s1[2]; sc[7]=s1[3];
            sc[8]=s2[0]; sc[9]=s2[1]; sc[10]=s2[2]; sc[11]=s2[3];
            sc[12]=s3[0]; sc[13]=s3[1]; sc[14]=s3[2]; sc[15]=s3[3];
        } else {
#pragma unroll
            for (int c = 0; c < 16; ++c) sc[c] = -INFINITY;
        }
#pragma unroll
        for (int c = 0; c < 16; ++c) scr[c * 65 + lane] = sc[c];
        float mc = -INFINITY;
#pragma unroll
        for (int j = 0; j < 16; ++j)
            mc = fmaxf(mc, scr[c16 * 65 + 4 * j + q4]);
        mc = fmaxf(mc, __shfl_xor(mc, 16));
        mc = fmaxf(mc, __shfl_xor(mc, 32));
        float m_new = fmaxf(m_run, mc);
        float ssum = 0.f;
#pragma unroll
        for (int j = 0; j < 16; ++j)
            ssum += __expf(scr[c16 * 65 + 4 * j + q4] - m_new);
        ssum += __shfl_xor(ssum, 16);
        ssum += __shfl_xor(ssum, 32);
        s_run = s_run * __expf(m_run - m_new) + ssum;
        m_run = m_new;
    }
    if (lane < 16) {
        ms[c16] = m_run;
        ms[16 + c16] = __builtin_amdgcn_rcpf(s_run);
    }

    float a0 = 0.f, a1 = 0.f, a2 = 0.f, a3 = 0.f;
    for (int base = 0; base < deg; base += 64) {
        int k = base + lane;
        int cn = min(64, deg - base);
        int src = 0;
        if (lane < cn) {
            int slot = beg + k;
            int eid = slot_eid[slot];
            src = slot_src[slot];
            const f32x4* sp = (const f32x4*)&sorted_sc[(size_t)slot * 16];
            f32x4 s0 = sp[0], s1 = sp[1], s2 = sp[2], s3 = sp[3];
            float sc[16];
            sc[0]=s0[0]; sc[1]=s0[1]; sc[2]=s0[2]; sc[3]=s0[3];
            sc[4]=s1[0]; sc[5]=s1[1]; sc[6]=s1[2]; sc[7]=s1[3];
            sc[8]=s2[0]; sc[9]=s2[1]; sc[10]=s2[2]; sc[11]=s2[3];
            sc[12]=s3[0]; sc[13]=s3[1]; sc[14]=s3[2]; sc[15]=s3[3];
            float w[8];
#pragma unroll
            for (int h = 0; h < 8; ++h) {
                f32x2 mp = *(const f32x2*)&ms[2 * h];
                f32x2 rp = *(const f32x2*)&ms[16 + 2 * h];
                w[h] = __expf(sc[2 * h] - mp[0]) * rp[0]
                     - beta * __expf(sc[2 * h + 1] - mp[1]) * rp[1];
            }
            f32x4 w0 = (f32x4){w[0], w[1], w[2], w[3]};
            f32x4 w1 = (f32x4){w[4], w[5], w[6], w[7]};
            *(f32x4*)&attn_out[(size_t)eid * 8]     = w0;
            *(f32x4*)&attn_out[(size_t)eid * 8 + 4] = w1;
            *(f32x4*)&scr[lane * 8]     = w0;
            *(f32x4*)&scr[lane * 8 + 4] = w1;
        }
        srcs[lane] = src;
        for (int kk = 0; kk < cn; ++kk) {
            float wk = scr[kk * 8 + hh];
            int sk = srcs[kk];
            bf16x4 v = *(const bf16x4*)&Vb[(size_t)sk * 256 + d0];
            a0 += wk * b2f(v[0]);
            a1 += wk * b2f(v[1]);
            a2 += wk * b2f(v[2]);
            a3 += wk * b2f(v[3]);
        }
    }
    bf16x4 r;
    r[0] = f2b(a0); r[1] = f2b(a1); r[2] = f2b(a2); r[3] = f2b(a3);
    *(bf16x4*)&accumb[(size_t)n * 256 + d0] = r;
}

extern "C" void kernel_launch(void* const* d_in, const int* in_sizes, int n_in,
                              void* d_out, int out_size, void* d_ws, size_t ws_size,
                              hipStream_t stream) {
    const float* x         = (const float*)d_in[0];
    const float* edge_attr = (const float*)d_in[1];
    const float* v_w       = (const float*)d_in[2];
    const float* out_w     = (const float*)d_in[3];
    const float* e_w1      = (const float*)d_in[4];
    const float* e_b1      = (const float*)d_in[5];
    const float* e_w2      = (const float*)d_in[6];
    const float* e_b2      = (const float*)d_in[7];
    const float* lq        = (const float*)d_in[8];
    const float* lk        = (const float*)d_in[9];
    const int*   ei        = (const int*)d_in[10];
    const int* srcp = ei;
    const int* tgtp = ei + N_EDGES;

    float* out = (float*)d_out;
    float* attn_out = out + (size_t)N_NODES * 256;
    float* beta_out = attn_out + (size_t)N_EDGES * 8;

    // workspace layout
    short* Vb       = (short*)d_ws;                             // N*256 bf16
    float* sorted_sc= (float*)(Vb + (size_t)N_NODES * 256);     // E*16 f32
    short* accumb   = (short*)(sorted_sc + (size_t)N_EDGES * 16); // N*256 bf16
    int*   cnt      = (int*)(accumb + (size_t)N_NODES * 256);
    int*   offs     = cnt + N_NODES;
    int*   cursor   = offs + N_NODES + 1;
    int*   partials = cursor + N_NODES;
    int*   slot_eid = partials + 256;                           // E ints
    int*   slot_src = slot_eid + N_EDGES;                       // E ints
    float* betap    = (float*)(slot_src + N_EDGES);

    const int NB = (N_NODES + 255) / 256;

    hipMemsetAsync(cnt, 0, N_NODES * sizeof(int), stream);

    // V(bf16) = x @ v_w.T  (+ fused tgt histogram)
    gemm_mfma_t<false, true><<<dim3((N_NODES + 127) / 128, 4), 256, 0, stream>>>(
        x, v_w, Vb, N_NODES, tgtp, cnt);

    scan1<<<NB, 256, 0, stream>>>(cnt, offs, partials, N_NODES);
    scan2<<<1, 256, 0, stream>>>(partials, NB, lq, lk, betap, beta_out);
    scan3<<<NB, 256, 0, stream>>>(offs, partials, cursor, N_NODES);

    // edge MLP -> sorted-slot scores (+ slot_eid/slot_src); scatter_eid is gone
    edge_mlp_mfma<<<N_EDGES / 256, 256, 0, stream>>>(edge_attr, e_w1, e_b1, e_w2, e_b2,
                                                     tgtp, srcp, cursor,
                                                     sorted_sc, slot_eid, slot_src);

    // fused softmax + aggregation (wave per node, coalesced slot reads)
    node_agg4<<<N_NODES / 4, 256, 0, stream>>>(slot_eid, offs, slot_src, sorted_sc,
                                               Vb, betap, accumb, attn_out);

    // out = accum(bf16) @ out_w.T
    gemm_mfma_t<true, false><<<dim3((N_NODES + 127) / 128, 4), 256, 0, stream>>>(
        accumb, out_w, out, N_NODES, nullptr, nullptr);
}